// Round 3
// baseline (1359.028 us; speedup 1.0000x reference)
//
#include <hip/hip_runtime.h>
#include <math.h>

#define TOK 4096      // B*S
#define DM 2048
#define SL 2048
#define NHEAD 16
#define DKH 128
#define DFF 8192

typedef float f32x4 __attribute__((ext_vector_type(4)));
typedef __bf16 bf16x8 __attribute__((ext_vector_type(8)));
typedef unsigned short u16x8 __attribute__((ext_vector_type(8)));

__device__ __forceinline__ unsigned short f2bf(float f) {
  unsigned int u = __float_as_uint(f);
  u += 0x7fffu + ((u >> 16) & 1u);
  return (unsigned short)(u >> 16);
}
__device__ __forceinline__ float bf2f(unsigned short h) {
  return __uint_as_float((unsigned int)h << 16);
}

__device__ __forceinline__ void gload_lds16(const void* g, void* l) {
  __builtin_amdgcn_global_load_lds(
      (const __attribute__((address_space(1))) unsigned int*)g,
      (__attribute__((address_space(3))) unsigned int*)l, 16, 0, 0);
}

// ---------------- fused dual layernorm (shared mean/var), fp32 -> bf16 x2 ----
__global__ __launch_bounds__(256) void ln_cast_kernel(
    const float* __restrict__ x, const float* __restrict__ g1,
    const float* __restrict__ be1, const float* __restrict__ g2,
    const float* __restrict__ be2, unsigned short* __restrict__ attn_in,
    unsigned short* __restrict__ ff_in) {
  __shared__ float redS[4], redQ[4];
  long row = blockIdx.x;
  int t = threadIdx.x;
  const float4* xr = (const float4*)(x + row * DM);
  float4 a = xr[t];
  float4 b = xr[t + 256];
  float s = a.x + a.y + a.z + a.w + b.x + b.y + b.z + b.w;
  float q = a.x * a.x + a.y * a.y + a.z * a.z + a.w * a.w +
            b.x * b.x + b.y * b.y + b.z * b.z + b.w * b.w;
  for (int o = 32; o > 0; o >>= 1) {
    s += __shfl_xor(s, o, 64);
    q += __shfl_xor(q, o, 64);
  }
  int wave = t >> 6;
  if ((t & 63) == 0) { redS[wave] = s; redQ[wave] = q; }
  __syncthreads();
  s = redS[0] + redS[1] + redS[2] + redS[3];
  q = redQ[0] + redQ[1] + redQ[2] + redQ[3];
  float mean = s * (1.0f / DM);
  float var = q * (1.0f / DM) - mean * mean;
  float rs = rsqrtf(var + 1e-5f);
  float vals[8] = {a.x, a.y, a.z, a.w, b.x, b.y, b.z, b.w};
  long base = row * DM;
#pragma unroll
  for (int i = 0; i < 8; ++i) {
    int c = (i < 4) ? (4 * t + i) : (1024 + 4 * t + (i - 4));
    float nv = (vals[i] - mean) * rs;
    attn_in[base + c] = f2bf(nv * g1[c] + be1[c]);
    ff_in[base + c] = f2bf(nv * g2[c] + be2[c]);
  }
}

// ---------------- fp32 [R,C] -> bf16 [C,R] ----------------------------------
__global__ __launch_bounds__(256) void transpose_cast(
    const float* __restrict__ in, unsigned short* __restrict__ out, int R, int C) {
  __shared__ float tile[32][33];
  int bx = blockIdx.x << 5;
  int by = blockIdx.y << 5;
  int tx = threadIdx.x & 31, ty = threadIdx.x >> 5;
#pragma unroll
  for (int i = ty; i < 32; i += 8) tile[i][tx] = in[(long)(by + i) * C + bx + tx];
  __syncthreads();
#pragma unroll
  for (int i = ty; i < 32; i += 8)
    out[(long)(bx + i) * R + by + tx] = f2bf(tile[tx][i]);
}

// ---------------- V slice of qkv (bf16) -> v_t[bh][dk][s] --------------------
__global__ __launch_bounds__(256) void transpose_v(
    const unsigned short* __restrict__ qkv, unsigned short* __restrict__ v_t) {
  __shared__ unsigned short tile[32][33];
  int z = blockIdx.z;
  int b = z >> 4, h = z & 15;
  int sx = blockIdx.x << 5;
  int dx = blockIdx.y << 5;
  int tx = threadIdx.x & 31, ty = threadIdx.x >> 5;
  const unsigned short* src = qkv + (long)b * SL * (3 * DM) + 2 * DM + h * DKH;
#pragma unroll
  for (int i = ty; i < 32; i += 8)
    tile[i][tx] = src[(long)(sx + i) * (3 * DM) + dx + tx];
  __syncthreads();
  unsigned short* dst = v_t + (long)z * DKH * SL;
#pragma unroll
  for (int i = ty; i < 32; i += 8)
    dst[(long)(dx + i) * SL + sx + tx] = tile[tx][i];
}

// ---------------- in-place row softmax on bf16 scores ------------------------
__global__ __launch_bounds__(256) void softmax_bf16(unsigned short* __restrict__ sc) {
  __shared__ float red[4];
  long row = blockIdx.x;
  unsigned short* rp = sc + row * (long)SL;
  int t = threadIdx.x, wave = t >> 6;
  u16x8 u = ((const u16x8*)rp)[t];
  const float scale = 0.08838834764831845f;  // 1/sqrt(128)
  float v[8];
  float mx = -1e30f;
#pragma unroll
  for (int i = 0; i < 8; ++i) { v[i] = bf2f(u[i]) * scale; mx = fmaxf(mx, v[i]); }
  for (int o = 32; o > 0; o >>= 1) mx = fmaxf(mx, __shfl_xor(mx, o, 64));
  if ((t & 63) == 0) red[wave] = mx;
  __syncthreads();
  mx = fmaxf(fmaxf(red[0], red[1]), fmaxf(red[2], red[3]));
  __syncthreads();
  float sum = 0.f;
#pragma unroll
  for (int i = 0; i < 8; ++i) { v[i] = __expf(v[i] - mx); sum += v[i]; }
  for (int o = 32; o > 0; o >>= 1) sum += __shfl_xor(sum, o, 64);
  if ((t & 63) == 0) red[wave] = sum;
  __syncthreads();
  float inv = 1.0f / (red[0] + red[1] + red[2] + red[3]);
  u16x8 o;
#pragma unroll
  for (int i = 0; i < 8; ++i) o[i] = f2bf(v[i] * inv);
  ((u16x8*)rp)[t] = o;  // same addr each thread read -> safe in place
}

// ---------------- f32 -> bf16 bulk cast --------------------------------------
__global__ __launch_bounds__(256) void cast_f2b(const float* __restrict__ in,
                                                unsigned short* __restrict__ out) {
  long i = ((long)blockIdx.x * 256 + threadIdx.x) * 8;
  float4 a = *(const float4*)(in + i);
  float4 b = *(const float4*)(in + i + 4);
  u16x8 o;
  o[0] = f2bf(a.x); o[1] = f2bf(a.y); o[2] = f2bf(a.z); o[3] = f2bf(a.w);
  o[4] = f2bf(b.x); o[5] = f2bf(b.y); o[6] = f2bf(b.z); o[7] = f2bf(b.w);
  *(u16x8*)(out + i) = o;
}

// ---------------- generic C = A * B^T bf16 MFMA GEMM -------------------------
// 128x128 tile, BK=32, XOR-swizzled LDS (conflict-free ds_read_b128).
// EPI: 0=bf16 store, 2=bias+gelu->bf16,
//      5=atomicAdd(out, acc + (kz==0 ? x : 0)),
//      6=atomicAdd(out, ls*acc + (kz==0 ? ls*bias : 0)),
//      7=atomicAdd(out, acc)
struct GemmP {
  const unsigned short* A;
  const unsigned short* B;
  const float* bias;
  const float* xadd;
  const float* lscale;
  float* outf;
  unsigned short* outb;
  int K;               // K per split part
  int lda, ldb, ldc;
  long sAz, sAo, sAi;
  long sBz, sBo, sBi;
  long sCz, sCo, sCi;
  int innerN, zbase, nksplit;
};

template <int EPI>
__global__ __launch_bounds__(256, 2) void gemm_bt(GemmP p) {
  __shared__ __align__(16) unsigned short As[128 * 32];
  __shared__ __align__(16) unsigned short Bs[128 * 32];
  const int tid = threadIdx.x;
  const int wave = tid >> 6;
  const int lane = tid & 63;
  const int quad = lane >> 4;
  const int l16 = lane & 15;
  const int wm = (wave >> 1) << 6;
  const int wn = (wave & 1) << 6;
  const long m0 = (long)blockIdx.y << 7;
  const long n0 = (long)blockIdx.x << 7;
  const int kz = blockIdx.z % p.nksplit;
  const int zlog = blockIdx.z / p.nksplit;
  const int zz = p.zbase + zlog;
  const int zq = zz / p.innerN;
  const int zr = zz - zq * p.innerN;
  const long koff = (long)kz * p.K;
  const unsigned short* Ab =
      p.A + (long)zlog * p.sAz + (long)zq * p.sAo + (long)zr * p.sAi + koff;
  const unsigned short* Bb =
      p.B + (long)zlog * p.sBz + (long)zq * p.sBo + (long)zr * p.sBi + koff;
  const long offC = (long)zlog * p.sCz + (long)zq * p.sCo + (long)zr * p.sCi;

  f32x4 acc[4][4];
#pragma unroll
  for (int i = 0; i < 4; ++i)
#pragma unroll
    for (int j = 0; j < 4; ++j)
#pragma unroll
      for (int r = 0; r < 4; ++r) acc[i][j][r] = 0.0f;

  // staging: flat chunk f in [0,512), 16B each; row = f>>2,
  // swizzled col8 = (f&3) ^ ((row>>1)&3)  (same swizzle for f and f+256)
  const int r0 = tid >> 2;
  const int r1 = r0 + 64;
  const int csw = (((tid & 3) ^ ((r0 >> 1) & 3)) << 3);
  unsigned short* lA0 = As + (long)(tid & ~63) * 8;  // wave-uniform base
  unsigned short* lA1 = As + (long)(256 + (tid & ~63)) * 8;
  unsigned short* lB0 = Bs + (long)(tid & ~63) * 8;
  unsigned short* lB1 = Bs + (long)(256 + (tid & ~63)) * 8;

  for (int k0 = 0; k0 < p.K; k0 += 32) {
    gload_lds16(Ab + (m0 + r0) * (long)p.lda + k0 + csw, lA0);
    gload_lds16(Ab + (m0 + r1) * (long)p.lda + k0 + csw, lA1);
    gload_lds16(Bb + (n0 + r0) * (long)p.ldb + k0 + csw, lB0);
    gload_lds16(Bb + (n0 + r1) * (long)p.ldb + k0 + csw, lB1);
    __syncthreads();
    bf16x8 af[4], bf[4];
#pragma unroll
    for (int i = 0; i < 4; ++i) {
      int rA = wm + i * 16 + l16;
      af[i] = *(const bf16x8*)(As + (((rA << 2) + (quad ^ ((rA >> 1) & 3))) << 3));
      int rB = wn + i * 16 + l16;
      bf[i] = *(const bf16x8*)(Bs + (((rB << 2) + (quad ^ ((rB >> 1) & 3))) << 3));
    }
#pragma unroll
    for (int i = 0; i < 4; ++i)
#pragma unroll
      for (int j = 0; j < 4; ++j)
        acc[i][j] =
            __builtin_amdgcn_mfma_f32_16x16x32_bf16(af[i], bf[j], acc[i][j], 0, 0, 0);
    __syncthreads();
  }

#pragma unroll
  for (int i = 0; i < 4; ++i)
#pragma unroll
    for (int j = 0; j < 4; ++j)
#pragma unroll
      for (int r = 0; r < 4; ++r) {
        long m = m0 + wm + i * 16 + quad * 4 + r;
        long n = n0 + wn + j * 16 + l16;
        long idx = offC + m * (long)p.ldc + n;
        float v = acc[i][j][r];
        if (EPI == 0) {
          p.outb[idx] = f2bf(v);
        } else if (EPI == 2) {
          float u = v + p.bias[n];
          p.outb[idx] = f2bf(0.5f * u * (1.0f + erff(u * 0.70710678118654752f)));
        } else if (EPI == 5) {
          float add = v + (kz == 0 ? p.xadd[m * (long)p.ldc + n] : 0.0f);
          atomicAdd(&p.outf[idx], add);
        } else if (EPI == 6) {
          float add = p.lscale[n] * v + (kz == 0 ? p.lscale[n] * p.bias[n] : 0.0f);
          atomicAdd(&p.outf[idx], add);
        } else {  // 7
          atomicAdd(&p.outf[idx], v);
        }
      }
}

// ----------------------------------------------------------------------------
// Workspace layout (MiB, liveness-overlaid; fixed part = 144 MiB):
//   [0,48)    qkv bf16        (QKV gemm .. end of attention)
//   [48,80)   ctx_f32         (attention loop .. cast)
//   [0,64)    h1 bf16         (FF1 .. FF2; qkv/ctx_f32 dead by then)
//   [80,96)   attn_in -> v_t -> ctx_bf16 (sequential liveness)
//   [96,112)  ff_in           (until FF1)
//   [112,144) wbuf            (one weight at a time; idle during attention loop)
//   [144,..)  scores bf16, chunk*8 MiB  (falls back onto wbuf if ws is tight)
extern "C" void kernel_launch(void* const* d_in, const int* in_sizes, int n_in,
                              void* d_out, int out_size, void* d_ws, size_t ws_size,
                              hipStream_t stream) {
  const float* x = (const float*)d_in[0];
  const float* w_qkv = (const float*)d_in[2];
  const float* w_o = (const float*)d_in[3];
  const float* g1 = (const float*)d_in[4];
  const float* be1 = (const float*)d_in[5];
  const float* g2 = (const float*)d_in[6];
  const float* be2 = (const float*)d_in[7];
  const float* w1 = (const float*)d_in[8];
  const float* b1 = (const float*)d_in[9];
  const float* w2 = (const float*)d_in[10];
  const float* b2 = (const float*)d_in[11];
  const float* ls = (const float*)d_in[12];
  float* out = (float*)d_out;

  unsigned char* ws = (unsigned char*)d_ws;
  const size_t MiB = 1024 * 1024;
  unsigned short* qkv = (unsigned short*)(ws);
  float* ctx_f32 = (float*)(ws + 48 * MiB);
  unsigned short* h1 = (unsigned short*)(ws);
  unsigned short* attn_in = (unsigned short*)(ws + 80 * MiB);
  unsigned short* v_t = (unsigned short*)(ws + 80 * MiB);
  unsigned short* ctx_bf = (unsigned short*)(ws + 80 * MiB);
  unsigned short* ff_in = (unsigned short*)(ws + 96 * MiB);
  unsigned short* wbuf = (unsigned short*)(ws + 112 * MiB);

  int chunk;
  unsigned short* scores;
  if (ws_size >= 400 * MiB)      { chunk = 32; scores = (unsigned short*)(ws + 144 * MiB); }
  else if (ws_size >= 272 * MiB) { chunk = 16; scores = (unsigned short*)(ws + 144 * MiB); }
  else if (ws_size >= 208 * MiB) { chunk = 8;  scores = (unsigned short*)(ws + 144 * MiB); }
  else if (ws_size >= 176 * MiB) { chunk = 4;  scores = (unsigned short*)(ws + 144 * MiB); }
  else if (ws_size >= 160 * MiB) { chunk = 2;  scores = (unsigned short*)(ws + 144 * MiB); }
  else                           { chunk = 4;  scores = (unsigned short*)(ws + 112 * MiB); }

  dim3 blk(256);

  hipMemsetAsync(out, 0, (size_t)TOK * DM * 4, stream);
  hipMemsetAsync(ctx_f32, 0, (size_t)TOK * DM * 4, stream);

  ln_cast_kernel<<<TOK, blk, 0, stream>>>(x, g1, be1, g2, be2, attn_in, ff_in);

  {  // qkv = attn_in @ w_qkv  (bf16 out)
    transpose_cast<<<dim3(3 * DM / 32, DM / 32), blk, 0, stream>>>(w_qkv, wbuf, DM, 3 * DM);
    GemmP p = {};
    p.A = attn_in; p.B = wbuf; p.outb = qkv;
    p.K = DM; p.lda = DM; p.ldb = DM; p.ldc = 3 * DM;
    p.innerN = 1; p.nksplit = 1;
    gemm_bt<0><<<dim3(3 * DM / 128, TOK / 128, 1), blk, 0, stream>>>(p);
  }

  transpose_v<<<dim3(SL / 32, DKH / 32, 32), blk, 0, stream>>>(qkv, v_t);

  for (int c0 = 0; c0 < 32; c0 += chunk) {
    {  // scores[z] = q(bh) @ k(bh)^T  (bf16 out, scale folded into softmax)
      GemmP p = {};
      p.A = qkv; p.B = qkv + DM; p.outb = scores;
      p.K = DKH; p.lda = 3 * DM; p.ldb = 3 * DM; p.ldc = SL;
      p.sAo = (long)SL * 3 * DM; p.sAi = DKH;
      p.sBo = (long)SL * 3 * DM; p.sBi = DKH;
      p.sCz = (long)SL * SL;
      p.innerN = NHEAD; p.zbase = c0; p.nksplit = 1;
      gemm_bt<0><<<dim3(SL / 128, SL / 128, chunk), blk, 0, stream>>>(p);
    }
    softmax_bf16<<<chunk * SL, blk, 0, stream>>>(scores);
    {  // ctx_f32(bh) += P @ V  (split-K x4, atomic f32)
      GemmP p = {};
      p.A = scores; p.B = v_t; p.outf = ctx_f32;
      p.K = SL / 4; p.lda = SL; p.ldb = SL; p.ldc = DM;
      p.sAz = (long)SL * SL;
      p.sBo = (long)NHEAD * DKH * SL; p.sBi = (long)DKH * SL;
      p.sCo = (long)SL * DM; p.sCi = DKH;
      p.innerN = NHEAD; p.zbase = c0; p.nksplit = 4;
      gemm_bt<7><<<dim3(DKH / 128, SL / 128, chunk * 4), blk, 0, stream>>>(p);
    }
  }

  cast_f2b<<<(TOK * DM) / (256 * 8), blk, 0, stream>>>(ctx_f32, ctx_bf);

  {  // out += ctx @ w_o + x   (split-K x4)
    transpose_cast<<<dim3(DM / 32, DM / 32), blk, 0, stream>>>(w_o, wbuf, DM, DM);
    GemmP p = {};
    p.A = ctx_bf; p.B = wbuf; p.outf = out; p.xadd = x;
    p.K = DM / 4; p.lda = DM; p.ldb = DM; p.ldc = DM;
    p.innerN = 1; p.nksplit = 4;
    gemm_bt<5><<<dim3(DM / 128, TOK / 128, 4), blk, 0, stream>>>(p);
  }
  {  // h1 = gelu(ff_in @ w1 + b1)  (bf16)
    transpose_cast<<<dim3(DFF / 32, DM / 32), blk, 0, stream>>>(w1, wbuf, DM, DFF);
    GemmP p = {};
    p.A = ff_in; p.B = wbuf; p.outb = h1; p.bias = b1;
    p.K = DM; p.lda = DM; p.ldb = DM; p.ldc = DFF;
    p.innerN = 1; p.nksplit = 1;
    gemm_bt<2><<<dim3(DFF / 128, TOK / 128, 1), blk, 0, stream>>>(p);
  }
  {  // out += layer_scale * (h1 @ w2 + b2)  (split-K x4)
    transpose_cast<<<dim3(DM / 32, DFF / 32), blk, 0, stream>>>(w2, wbuf, DFF, DM);
    GemmP p = {};
    p.A = h1; p.B = wbuf; p.outf = out; p.bias = b2; p.lscale = ls;
    p.K = DFF / 4; p.lda = DFF; p.ldb = DFF; p.ldc = DM;
    p.innerN = 1; p.nksplit = 4;
    gemm_bt<6><<<dim3(DM / 128, TOK / 128, 4), blk, 0, stream>>>(p);
  }
}

// Round 4
// 1110.179 us; speedup vs baseline: 1.2242x; 1.2242x over previous
//
#include <hip/hip_runtime.h>
#include <math.h>

#define TOK 4096      // B*S
#define DM 2048
#define SL 2048
#define NHEAD 16
#define DKH 128
#define DFF 8192

typedef float f32x4 __attribute__((ext_vector_type(4)));
typedef __bf16 bf16x8 __attribute__((ext_vector_type(8)));
typedef unsigned short u16x8 __attribute__((ext_vector_type(8)));

__device__ __forceinline__ unsigned short f2bf(float f) {
  unsigned int u = __float_as_uint(f);
  u += 0x7fffu + ((u >> 16) & 1u);
  return (unsigned short)(u >> 16);
}
__device__ __forceinline__ float bf2f(unsigned short h) {
  return __uint_as_float((unsigned int)h << 16);
}

__device__ __forceinline__ void gload_lds16(const void* g, void* l) {
  __builtin_amdgcn_global_load_lds(
      (const __attribute__((address_space(1))) unsigned int*)g,
      (__attribute__((address_space(3))) unsigned int*)l, 16, 0, 0);
}

// ---------------- fused dual layernorm (shared mean/var), fp32 -> bf16 x2 ----
__global__ __launch_bounds__(256) void ln_cast_kernel(
    const float* __restrict__ x, const float* __restrict__ g1,
    const float* __restrict__ be1, const float* __restrict__ g2,
    const float* __restrict__ be2, unsigned short* __restrict__ attn_in,
    unsigned short* __restrict__ ff_in) {
  __shared__ float redS[4], redQ[4];
  long row = blockIdx.x;
  int t = threadIdx.x;
  const float4* xr = (const float4*)(x + row * DM);
  float4 a = xr[t];
  float4 b = xr[t + 256];
  float s = a.x + a.y + a.z + a.w + b.x + b.y + b.z + b.w;
  float q = a.x * a.x + a.y * a.y + a.z * a.z + a.w * a.w +
            b.x * b.x + b.y * b.y + b.z * b.z + b.w * b.w;
  for (int o = 32; o > 0; o >>= 1) {
    s += __shfl_xor(s, o, 64);
    q += __shfl_xor(q, o, 64);
  }
  int wave = t >> 6;
  if ((t & 63) == 0) { redS[wave] = s; redQ[wave] = q; }
  __syncthreads();
  s = redS[0] + redS[1] + redS[2] + redS[3];
  q = redQ[0] + redQ[1] + redQ[2] + redQ[3];
  float mean = s * (1.0f / DM);
  float var = q * (1.0f / DM) - mean * mean;
  float rs = rsqrtf(var + 1e-5f);
  float vals[8] = {a.x, a.y, a.z, a.w, b.x, b.y, b.z, b.w};
  long base = row * DM;
#pragma unroll
  for (int i = 0; i < 8; ++i) {
    int c = (i < 4) ? (4 * t + i) : (1024 + 4 * t + (i - 4));
    float nv = (vals[i] - mean) * rs;
    attn_in[base + c] = f2bf(nv * g1[c] + be1[c]);
    ff_in[base + c] = f2bf(nv * g2[c] + be2[c]);
  }
}

// ---------------- fp32 [R,C] -> bf16 [C,R] ----------------------------------
__global__ __launch_bounds__(256) void transpose_cast(
    const float* __restrict__ in, unsigned short* __restrict__ out, int R, int C) {
  __shared__ float tile[32][33];
  int bx = blockIdx.x << 5;
  int by = blockIdx.y << 5;
  int tx = threadIdx.x & 31, ty = threadIdx.x >> 5;
#pragma unroll
  for (int i = ty; i < 32; i += 8) tile[i][tx] = in[(long)(by + i) * C + bx + tx];
  __syncthreads();
#pragma unroll
  for (int i = ty; i < 32; i += 8)
    out[(long)(bx + i) * R + by + tx] = f2bf(tile[tx][i]);
}

// ---------------- V slice of qkv (bf16) -> v_t[bh][dk][s] --------------------
__global__ __launch_bounds__(256) void transpose_v(
    const unsigned short* __restrict__ qkv, unsigned short* __restrict__ v_t) {
  __shared__ unsigned short tile[32][33];
  int z = blockIdx.z;
  int b = z >> 4, h = z & 15;
  int sx = blockIdx.x << 5;
  int dx = blockIdx.y << 5;
  int tx = threadIdx.x & 31, ty = threadIdx.x >> 5;
  const unsigned short* src = qkv + (long)b * SL * (3 * DM) + 2 * DM + h * DKH;
#pragma unroll
  for (int i = ty; i < 32; i += 8)
    tile[i][tx] = src[(long)(sx + i) * (3 * DM) + dx + tx];
  __syncthreads();
  unsigned short* dst = v_t + (long)z * DKH * SL;
#pragma unroll
  for (int i = ty; i < 32; i += 8)
    dst[(long)(dx + i) * SL + sx + tx] = tile[tx][i];
}

// ---------------- in-place row softmax on bf16 scores ------------------------
__global__ __launch_bounds__(256) void softmax_bf16(unsigned short* __restrict__ sc) {
  __shared__ float red[4];
  long row = blockIdx.x;
  unsigned short* rp = sc + row * (long)SL;
  int t = threadIdx.x, wave = t >> 6;
  u16x8 u = ((const u16x8*)rp)[t];
  const float scale = 0.08838834764831845f;  // 1/sqrt(128)
  float v[8];
  float mx = -1e30f;
#pragma unroll
  for (int i = 0; i < 8; ++i) { v[i] = bf2f(u[i]) * scale; mx = fmaxf(mx, v[i]); }
  for (int o = 32; o > 0; o >>= 1) mx = fmaxf(mx, __shfl_xor(mx, o, 64));
  if ((t & 63) == 0) red[wave] = mx;
  __syncthreads();
  mx = fmaxf(fmaxf(red[0], red[1]), fmaxf(red[2], red[3]));
  __syncthreads();
  float sum = 0.f;
#pragma unroll
  for (int i = 0; i < 8; ++i) { v[i] = __expf(v[i] - mx); sum += v[i]; }
  for (int o = 32; o > 0; o >>= 1) sum += __shfl_xor(sum, o, 64);
  if ((t & 63) == 0) red[wave] = sum;
  __syncthreads();
  float inv = 1.0f / (red[0] + red[1] + red[2] + red[3]);
  u16x8 o;
#pragma unroll
  for (int i = 0; i < 8; ++i) o[i] = f2bf(v[i] * inv);
  ((u16x8*)rp)[t] = o;  // same addr each thread read -> safe in place
}

// ---------------- combine kernels (split-K partial merge) --------------------
__global__ __launch_bounds__(256) void combine_ctx(unsigned short* __restrict__ c0,
                                                   const unsigned short* __restrict__ c1) {
  long i = (long)blockIdx.x * 256 + threadIdx.x;
  u16x8 a = ((const u16x8*)c0)[i];
  u16x8 b = ((const u16x8*)c1)[i];
  u16x8 o;
#pragma unroll
  for (int j = 0; j < 8; ++j) o[j] = f2bf(bf2f(a[j]) + bf2f(b[j]));
  ((u16x8*)c0)[i] = o;
}

__global__ __launch_bounds__(256) void combine_wo(const float* __restrict__ x,
                                                  const unsigned short* __restrict__ p0,
                                                  const unsigned short* __restrict__ p1,
                                                  float* __restrict__ out) {
  long i = ((long)blockIdx.x * 256 + threadIdx.x) * 8;
  u16x8 a = *(const u16x8*)(p0 + i);
  u16x8 b = *(const u16x8*)(p1 + i);
#pragma unroll
  for (int j = 0; j < 8; ++j) out[i + j] = x[i + j] + bf2f(a[j]) + bf2f(b[j]);
}

__global__ __launch_bounds__(256) void combine_ff(const unsigned short* __restrict__ p0,
                                                  const unsigned short* __restrict__ p1,
                                                  const float* __restrict__ ls,
                                                  const float* __restrict__ b2,
                                                  float* __restrict__ out) {
  long i = ((long)blockIdx.x * 256 + threadIdx.x) * 8;
  u16x8 a = *(const u16x8*)(p0 + i);
  u16x8 b = *(const u16x8*)(p1 + i);
#pragma unroll
  for (int j = 0; j < 8; ++j) {
    int col = (int)((i + j) & (DM - 1));
    out[i + j] += ls[col] * (bf2f(a[j]) + bf2f(b[j]) + b2[col]);
  }
}

// ---------------- generic C = A * B^T bf16 MFMA GEMM -------------------------
// 128x128 tile, BK=32, XOR-swizzled LDS (0 bank conflicts, verified R3).
// EPI: 0=bf16 store (supports split-K partials via sKz), 2=bias+gelu->bf16,
//      3=out=x+acc (f32), 4=out+=ls*(acc+bias) (f32 RMW fallback)
struct GemmP {
  const unsigned short* A;
  const unsigned short* B;
  const float* bias;
  const float* xadd;
  const float* lscale;
  float* outf;
  unsigned short* outb;
  int K;               // K per split part
  int lda, ldb, ldc;
  long sAz, sAo, sAi;
  long sBz, sBo, sBi;
  long sCz, sCo, sCi;
  long sKz;            // element stride between split-K partial buffers
  int innerN, zbase, nksplit;
};

template <int EPI>
__global__ __launch_bounds__(256, 2) void gemm_bt(GemmP p) {
  __shared__ __align__(16) unsigned short As[128 * 32];
  __shared__ __align__(16) unsigned short Bs[128 * 32];
  const int tid = threadIdx.x;
  const int wave = tid >> 6;
  const int lane = tid & 63;
  const int quad = lane >> 4;
  const int l16 = lane & 15;
  const int wm = (wave >> 1) << 6;
  const int wn = (wave & 1) << 6;
  const long m0 = (long)blockIdx.y << 7;
  const long n0 = (long)blockIdx.x << 7;
  const int kz = blockIdx.z % p.nksplit;
  const int zlog = blockIdx.z / p.nksplit;
  const int zz = p.zbase + zlog;
  const int zq = zz / p.innerN;
  const int zr = zz - zq * p.innerN;
  const long koff = (long)kz * p.K;
  const unsigned short* Ab =
      p.A + (long)zlog * p.sAz + (long)zq * p.sAo + (long)zr * p.sAi + koff;
  const unsigned short* Bb =
      p.B + (long)zlog * p.sBz + (long)zq * p.sBo + (long)zr * p.sBi + koff;
  const long offC =
      (long)zlog * p.sCz + (long)zq * p.sCo + (long)zr * p.sCi + (long)kz * p.sKz;

  f32x4 acc[4][4];
#pragma unroll
  for (int i = 0; i < 4; ++i)
#pragma unroll
    for (int j = 0; j < 4; ++j)
#pragma unroll
      for (int r = 0; r < 4; ++r) acc[i][j][r] = 0.0f;

  // staging: flat chunk f in [0,512), 16B each; row = f>>2,
  // swizzled col8 = (f&3) ^ ((row>>1)&3)
  const int r0 = tid >> 2;
  const int r1 = r0 + 64;
  const int csw = (((tid & 3) ^ ((r0 >> 1) & 3)) << 3);
  unsigned short* lA0 = As + (long)(tid & ~63) * 8;  // wave-uniform base
  unsigned short* lA1 = As + (long)(256 + (tid & ~63)) * 8;
  unsigned short* lB0 = Bs + (long)(tid & ~63) * 8;
  unsigned short* lB1 = Bs + (long)(256 + (tid & ~63)) * 8;

  for (int k0 = 0; k0 < p.K; k0 += 32) {
    gload_lds16(Ab + (m0 + r0) * (long)p.lda + k0 + csw, lA0);
    gload_lds16(Ab + (m0 + r1) * (long)p.lda + k0 + csw, lA1);
    gload_lds16(Bb + (n0 + r0) * (long)p.ldb + k0 + csw, lB0);
    gload_lds16(Bb + (n0 + r1) * (long)p.ldb + k0 + csw, lB1);
    __syncthreads();
    bf16x8 af[4], bf[4];
#pragma unroll
    for (int i = 0; i < 4; ++i) {
      int rA = wm + i * 16 + l16;
      af[i] = *(const bf16x8*)(As + (((rA << 2) + (quad ^ ((rA >> 1) & 3))) << 3));
      int rB = wn + i * 16 + l16;
      bf[i] = *(const bf16x8*)(Bs + (((rB << 2) + (quad ^ ((rB >> 1) & 3))) << 3));
    }
#pragma unroll
    for (int i = 0; i < 4; ++i)
#pragma unroll
      for (int j = 0; j < 4; ++j)
        acc[i][j] =
            __builtin_amdgcn_mfma_f32_16x16x32_bf16(af[i], bf[j], acc[i][j], 0, 0, 0);
    __syncthreads();
  }

#pragma unroll
  for (int i = 0; i < 4; ++i)
#pragma unroll
    for (int j = 0; j < 4; ++j)
#pragma unroll
      for (int r = 0; r < 4; ++r) {
        long m = m0 + wm + i * 16 + quad * 4 + r;
        long n = n0 + wn + j * 16 + l16;
        long idx = offC + m * (long)p.ldc + n;
        float v = acc[i][j][r];
        if (EPI == 0) {
          p.outb[idx] = f2bf(v);
        } else if (EPI == 2) {
          float u = v + p.bias[n];
          p.outb[idx] = f2bf(0.5f * u * (1.0f + erff(u * 0.70710678118654752f)));
        } else if (EPI == 3) {
          p.outf[idx] = p.xadd[m * (long)p.ldc + n] + v;
        } else {  // 4
          p.outf[idx] += p.lscale[n] * (v + p.bias[n]);
        }
      }
}

// ----------------------------------------------------------------------------
// Workspace layout (MiB, liveness-overlaid):
//   [0,48)    qkv bf16        (QKV gemm .. end of attention loop)
//   [48,64)   v_t bf16        (after QKV .. end of PV)
//   [64,80)   ff_in bf16      (until FF1)
//   [80,96)   attn_in bf16 -> PV partial C0 (= ctx_bf after combine)
//   [96,112)  PV partial C1   (inside wbuf region; consumed before w_o transpose)
//   [96,128)  wbuf            (one weight at a time; idle during attention loop)
//   [128,..)  scores bf16 chunk*8 MiB (loop) -> P0,P1 bf16 partials 32 MiB (after)
//   h1 overlays [0,64) during FF1/FF2 (qkv/v_t dead).
extern "C" void kernel_launch(void* const* d_in, const int* in_sizes, int n_in,
                              void* d_out, int out_size, void* d_ws, size_t ws_size,
                              hipStream_t stream) {
  const float* x = (const float*)d_in[0];
  const float* w_qkv = (const float*)d_in[2];
  const float* w_o = (const float*)d_in[3];
  const float* g1 = (const float*)d_in[4];
  const float* be1 = (const float*)d_in[5];
  const float* g2 = (const float*)d_in[6];
  const float* be2 = (const float*)d_in[7];
  const float* w1 = (const float*)d_in[8];
  const float* b1 = (const float*)d_in[9];
  const float* w2 = (const float*)d_in[10];
  const float* b2 = (const float*)d_in[11];
  const float* ls = (const float*)d_in[12];
  float* out = (float*)d_out;

  unsigned char* ws = (unsigned char*)d_ws;
  const size_t MiB = 1024 * 1024;
  unsigned short* qkv = (unsigned short*)(ws);
  unsigned short* v_t = (unsigned short*)(ws + 48 * MiB);
  unsigned short* ff_in = (unsigned short*)(ws + 64 * MiB);
  unsigned short* attn_in = (unsigned short*)(ws + 80 * MiB);
  unsigned short* ctxC0 = (unsigned short*)(ws + 80 * MiB);  // = ctx_bf
  unsigned short* ctxC1 = (unsigned short*)(ws + 96 * MiB);
  unsigned short* wbuf = (unsigned short*)(ws + 96 * MiB);
  unsigned short* h1 = (unsigned short*)(ws);
  unsigned short* scores = (unsigned short*)(ws + 128 * MiB);
  unsigned short* P0 = (unsigned short*)(ws + 128 * MiB);
  unsigned short* P1 = (unsigned short*)(ws + 144 * MiB);

  int chunk;
  bool split;
  if (ws_size >= 264 * MiB)      { chunk = 16; split = true; }
  else if (ws_size >= 196 * MiB) { chunk = 8;  split = true; }
  else if (ws_size >= 162 * MiB) { chunk = 4;  split = true; }
  else                           { chunk = 2;  split = false; }

  const long ODM = (long)TOK * DM;  // elements in one [TOK,DM] partial
  dim3 blk(256);

  ln_cast_kernel<<<TOK, blk, 0, stream>>>(x, g1, be1, g2, be2, attn_in, ff_in);

  {  // qkv = attn_in @ w_qkv  (bf16 out)
    transpose_cast<<<dim3(3 * DM / 32, DM / 32), blk, 0, stream>>>(w_qkv, wbuf, DM, 3 * DM);
    GemmP p = {};
    p.A = attn_in; p.B = wbuf; p.outb = qkv;
    p.K = DM; p.lda = DM; p.ldb = DM; p.ldc = 3 * DM;
    p.innerN = 1; p.nksplit = 1;
    gemm_bt<0><<<dim3(3 * DM / 128, TOK / 128, 1), blk, 0, stream>>>(p);
  }

  transpose_v<<<dim3(SL / 32, DKH / 32, 32), blk, 0, stream>>>(qkv, v_t);

  for (int c0 = 0; c0 < 32; c0 += chunk) {
    {  // scores[z] = q(bh) @ k(bh)^T  (bf16, scale folded into softmax)
      GemmP p = {};
      p.A = qkv; p.B = qkv + DM; p.outb = scores;
      p.K = DKH; p.lda = 3 * DM; p.ldb = 3 * DM; p.ldc = SL;
      p.sAo = (long)SL * 3 * DM; p.sAi = DKH;
      p.sBo = (long)SL * 3 * DM; p.sBi = DKH;
      p.sCz = (long)SL * SL;
      p.innerN = NHEAD; p.zbase = c0; p.nksplit = 1;
      gemm_bt<0><<<dim3(SL / 128, SL / 128, chunk), blk, 0, stream>>>(p);
    }
    softmax_bf16<<<chunk * SL, blk, 0, stream>>>(scores);
    {  // ctx partials (bh) = P @ V   (split-K x2 into C0/C1, plain bf16 stores)
      GemmP p = {};
      p.A = scores; p.B = v_t; p.outb = ctxC0;
      p.K = split ? SL / 2 : SL; p.lda = SL; p.ldb = SL; p.ldc = DM;
      p.sAz = (long)SL * SL;
      p.sBo = (long)NHEAD * DKH * SL; p.sBi = (long)DKH * SL;
      p.sCo = (long)SL * DM; p.sCi = DKH;
      p.sKz = ODM;
      p.innerN = NHEAD; p.zbase = c0; p.nksplit = split ? 2 : 1;
      gemm_bt<0><<<dim3(DKH / 128, SL / 128, chunk * p.nksplit), blk, 0, stream>>>(p);
    }
  }
  if (split)  // ctx_bf = C0 + C1 (in place into C0)
    combine_ctx<<<(int)(ODM / 2048), blk, 0, stream>>>(ctxC0, ctxC1);

  {  // attn_out = ctx @ w_o ;  out = x + attn_out
    transpose_cast<<<dim3(DM / 32, DM / 32), blk, 0, stream>>>(w_o, wbuf, DM, DM);
    GemmP p = {};
    p.A = ctxC0; p.B = wbuf;
    p.K = split ? DM / 2 : DM; p.lda = DM; p.ldb = DM; p.ldc = DM;
    p.sKz = ODM; p.innerN = 1; p.nksplit = split ? 2 : 1;
    if (split) {
      p.outb = P0;
      gemm_bt<0><<<dim3(DM / 128, TOK / 128, 2), blk, 0, stream>>>(p);
      combine_wo<<<(int)(ODM / 2048), blk, 0, stream>>>(x, P0, P1, out);
    } else {
      p.outf = out; p.xadd = x;
      gemm_bt<3><<<dim3(DM / 128, TOK / 128, 1), blk, 0, stream>>>(p);
    }
  }
  {  // h1 = gelu(ff_in @ w1 + b1)  (bf16) — overlays qkv/v_t
    transpose_cast<<<dim3(DFF / 32, DM / 32), blk, 0, stream>>>(w1, wbuf, DM, DFF);
    GemmP p = {};
    p.A = ff_in; p.B = wbuf; p.outb = h1; p.bias = b1;
    p.K = DM; p.lda = DM; p.ldb = DM; p.ldc = DFF;
    p.innerN = 1; p.nksplit = 1;
    gemm_bt<2><<<dim3(DFF / 128, TOK / 128, 1), blk, 0, stream>>>(p);
  }
  {  // out += layer_scale * (h1 @ w2 + b2)
    transpose_cast<<<dim3(DM / 32, DFF / 32), blk, 0, stream>>>(w2, wbuf, DFF, DM);
    GemmP p = {};
    p.A = h1; p.B = wbuf;
    p.K = split ? DFF / 2 : DFF; p.lda = DFF; p.ldb = DFF; p.ldc = DM;
    p.sKz = ODM; p.innerN = 1; p.nksplit = split ? 2 : 1;
    if (split) {
      p.outb = P0;
      gemm_bt<0><<<dim3(DM / 128, TOK / 128, 2), blk, 0, stream>>>(p);
      combine_ff<<<(int)(ODM / 2048), blk, 0, stream>>>(P0, P1, ls, b2, out);
    } else {
      p.outf = out; p.bias = b2; p.lscale = ls;
      gemm_bt<4><<<dim3(DM / 128, TOK / 128, 1), blk, 0, stream>>>(p);
    }
  }
}